// Round 6
// baseline (1463.607 us; speedup 1.0000x reference)
//
#include <hip/hip_runtime.h>
#include <hip/hip_bf16.h>
#include <stdint.h>

#define T_  32
#define B_  32
#define C_  128
#define HS_ 512
#define HW_ 7
#define S_  49
#define CS_  (C_*S_)      // 6272
#define ICS_ (2*C_*S_)    // 12544
#define KH_  1152         // per-half conv K (9*128), kid-major: k = kid*128+ic
#define KL_  6272         // linear K, reordered to k' = s*128+c
#define M_   1568         // B*S
#define MR_  1600         // M rounded to 64
#define N_   512

typedef __attribute__((ext_vector_type(8))) short short8;
typedef __attribute__((ext_vector_type(4))) float f32x4;
typedef __hip_bfloat16 bf16;

union bfbits { bf16 b; short s; };

__device__ __forceinline__ void gl16(const void* g, void* l) {
    __builtin_amdgcn_global_load_lds((const __attribute__((address_space(1))) void*)g,
                                     (__attribute__((address_space(3))) void*)l, 16, 0, 0);
}

__device__ __forceinline__ float sigm_f(float v) { return 1.0f / (1.0f + __expf(-v)); }
__device__ __forceinline__ float tanh_f(float v) { return 1.0f - 2.0f / (__expf(2.0f * v) + 1.0f); }

// Counted-vmcnt barrier (T3/T4): stage st+1 landed, stage st+2 stays in flight.
#define PIPE_BARRIER_COUNTED()  do {                                   \
    asm volatile("s_waitcnt vmcnt(8)" ::: "memory");                   \
    __builtin_amdgcn_sched_barrier(0);                                 \
    __builtin_amdgcn_s_barrier();                                      \
    __builtin_amdgcn_sched_barrier(0);                                 \
} while (0)
#define PIPE_BARRIER_DRAIN()  do {                                     \
    asm volatile("s_waitcnt vmcnt(0)" ::: "memory");                   \
    __builtin_amdgcn_sched_barrier(0);                                 \
    __builtin_amdgcn_s_barrier();                                      \
    __builtin_amdgcn_sched_barrier(0);                                 \
} while (0)

// ---------------------------------------------------------------------------
// Fused conv-GEMM + LSTM gates. Tile 64x64, 4 waves (2x2), BK=128 (1 K-step
// = one 3x3 tap = contiguous 128-ch read/row). 3-deep LDS pipeline with
// counted vmcnt: loads for stage st+2 remain in flight across the barrier.
// mode0: C = Ax*Wx + Ah*Wh + bias (18 steps, two accumulators, stores Gx).
// mode1: C = Gx + Ah*Wh (9 steps).
// ---------------------------------------------------------------------------
__global__ __launch_bounds__(256, 1) void k_fgemm(
    const bf16* __restrict__ xTt, const bf16* __restrict__ hT,
    bf16* __restrict__ hTN,
    const bf16* __restrict__ WxP, const bf16* __restrict__ WhP,
    const float* __restrict__ bconv,
    float* __restrict__ Gx, float* __restrict__ cbuf,
    const float* __restrict__ mask_c, const float* __restrict__ mask_a,
    bf16* __restrict__ chist_t, const bf16* __restrict__ zb, int mode0)
{
    __shared__ __align__(16) uint8_t smem[98304];
    bf16* sA = (bf16*)smem;                       // [3][64*128]
    bf16* sB = (bf16*)(smem + 49152);             // [3][64*128]
    float (*gld)[68] = (float(*)[68])smem;        // overlaid post-loop (17.4KB)

    const int tid = threadIdx.x, lane = tid & 63, w = tid >> 6;
    const int wr = w >> 1, wc = w & 1;
    const int m0 = blockIdx.x * 64, n0 = blockIdx.y * 64;

    // staging geometry: chunkslot = q*256+tid -> row r=q*16+(tid>>4), chunk kq=tid&15
    const int kq = tid & 15, rr = tid >> 4;
    const int swz = ((kq ^ rr) << 3);             // source elem offset (involution)
    int abS[4], ay[4], ax[4]; bool rok[4];
#pragma unroll
    for (int q = 0; q < 4; ++q) {
        int ra = m0 + q * 16 + rr;
        rok[q] = ra < M_;
        int b = ra / S_, s = ra - b * S_;
        abS[q] = b * S_;
        ay[q] = s / HW_; ax[q] = s - ay[q] * HW_;
    }

    const int NS = mode0 ? 18 : 9;

    f32x4 accX[2][2], accH[2][2];
    if (mode0) {
#pragma unroll
        for (int fn = 0; fn < 2; ++fn) {
            int np = n0 + wc * 32 + fn * 16 + (lane & 15);
            float bv = bconv[((np & 3) << 7) + (np >> 2)];
            f32x4 b4 = {bv, bv, bv, bv};
            accX[0][fn] = b4; accX[1][fn] = b4;
            f32x4 z4 = {0.f, 0.f, 0.f, 0.f};
            accH[0][fn] = z4; accH[1][fn] = z4;
        }
    } else {
#pragma unroll
        for (int fm = 0; fm < 2; ++fm) {
            int row = m0 + wr * 32 + fm * 16 + ((lane >> 4) << 2);
#pragma unroll
            for (int fn = 0; fn < 2; ++fn) {
                int col = n0 + wc * 32 + fn * 16 + (lane & 15);
#pragma unroll
                for (int j = 0; j < 4; ++j)
                    accH[fm][fn][j] = Gx[(size_t)(row + j) * N_ + col];
            }
        }
    }

    auto stage = [&](int st, int dbuf) {
        int xph = (mode0 && st < 9);
        int kid = xph ? st : (mode0 ? st - 9 : st);
        int ky = kid / 3, kx = kid - ky * 3;
        const bf16* Asrc = xph ? xTt : hT;
        const bf16* Wsrc = xph ? WxP : WhP;
        bf16* lA = sA + dbuf * 8192;
        bf16* lB = sB + dbuf * 8192;
#pragma unroll
        for (int q = 0; q < 4; ++q) {
            int y2 = ay[q] + ky - 1, x2 = ax[q] + kx - 1;
            const bf16* rb = (rok[q] && (unsigned)y2 < (unsigned)HW_ && (unsigned)x2 < (unsigned)HW_)
                ? Asrc + (((size_t)(abS[q] + y2 * HW_ + x2)) << 7) : zb;
            gl16(rb + swz, lA + q * 2048 + w * 512);
            gl16(Wsrc + (size_t)(n0 + q * 16 + rr) * KH_ + kid * 128 + swz, lB + q * 2048 + w * 512);
        }
    };

    auto compute = [&](int dbuf, f32x4 (&acc)[2][2]) {
        const bf16* lA = sA + dbuf * 8192;
        const bf16* lB = sB + dbuf * 8192;
        short8 af[2][4], bq[2][4];
#pragma unroll
        for (int kh = 0; kh < 4; ++kh) {
            int c = kh * 4 + (lane >> 4);
            int xr = (c ^ (lane & 15)) << 3;
#pragma unroll
            for (int fm = 0; fm < 2; ++fm) {
                int r = wr * 32 + fm * 16 + (lane & 15);
                af[fm][kh] = *(const short8*)(lA + r * 128 + xr);
            }
#pragma unroll
            for (int fn = 0; fn < 2; ++fn) {
                int r = wc * 32 + fn * 16 + (lane & 15);
                bq[fn][kh] = *(const short8*)(lB + r * 128 + xr);
            }
        }
#pragma unroll
        for (int kh = 0; kh < 4; ++kh)
#pragma unroll
            for (int fm = 0; fm < 2; ++fm)
#pragma unroll
                for (int fn = 0; fn < 2; ++fn)
                    acc[fm][fn] = __builtin_amdgcn_mfma_f32_16x16x32_bf16(
                        af[fm][kh], bq[fn][kh], acc[fm][fn], 0, 0, 0);
    };

    // prologue: two stages in flight, wait for the first only
    stage(0, 0);
    stage(1, 1);
    PIPE_BARRIER_COUNTED();

    int cur = 0;
#pragma unroll 1
    for (int st = 0; st < NS; ++st) {
        int pre = cur + 2; if (pre >= 3) pre -= 3;
        if (st + 2 < NS) stage(st + 2, pre);
        if (mode0 && st < 9) compute(cur, accX);
        else                 compute(cur, accH);
        if (st + 2 < NS) { PIPE_BARRIER_COUNTED(); }
        else             { PIPE_BARRIER_DRAIN(); }
        ++cur; if (cur == 3) cur = 0;
    }
    __syncthreads();   // full drain before LDS overlay

    if (mode0) {
#pragma unroll
        for (int fm = 0; fm < 2; ++fm) {
            int row = m0 + wr * 32 + fm * 16 + ((lane >> 4) << 2);
#pragma unroll
            for (int fn = 0; fn < 2; ++fn) {
                int col = n0 + wc * 32 + fn * 16 + (lane & 15);
#pragma unroll
                for (int j = 0; j < 4; ++j) {
                    Gx[(size_t)(row + j) * N_ + col] = accX[fm][fn][j];
                    accH[fm][fn][j] += accX[fm][fn][j];
                }
            }
        }
    }

    // acc -> LDS (aliases sA; loop fully drained above)
#pragma unroll
    for (int fm = 0; fm < 2; ++fm)
#pragma unroll
        for (int fn = 0; fn < 2; ++fn) {
            int row = wr * 32 + fm * 16 + ((lane >> 4) << 2);
            int col = wc * 32 + fn * 16 + (lane & 15);
#pragma unroll
            for (int j = 0; j < 4; ++j) gld[row + j][col] = accH[fm][fn][j];
        }
    __syncthreads();

#pragma unroll
    for (int q2 = 0; q2 < 4; ++q2) {
        int e = tid + q2 * 256;                   // 1024 = 64 rows x 16 channels
        int row = e >> 4, cc = e & 15;
        int m = m0 + row;
        if (m >= M_) continue;
        int b = m / S_, s = m - b * S_;
        int cg = (n0 >> 2) + cc;
        float g0 = gld[row][cc * 4 + 0], g1 = gld[row][cc * 4 + 1];
        float g2 = gld[row][cc * 4 + 2], g3 = gld[row][cc * 4 + 3];
        float ig = sigm_f(g0);
        float fg = sigm_f(g1);
        float og = sigm_f(g2);
        float gg = tanh_f(g3);
        size_t ci = (((size_t)b * S_ + s) << 7) + cg;
        float co = cbuf[ci];
        if (mask_c) co *= mask_c[b];
        float cn = fg * co + ig * gg;
        cbuf[ci] = cn;
        float hn = og * tanh_f(cn);
        float am = mask_a ? mask_a[b] : 1.f;
        hTN[ci] = __float2bfloat16(hn * am);
        if (chist_t) chist_t[(size_t)b * KL_ + s * C_ + cg] = __float2bfloat16(cn);
    }
}

// ---------------------------------------------------------------------------
// Deferred linear: out = relu(chist @ Wlp^T + blin). 64x64 tile, BK=128,
// same 3-deep counted-vmcnt pipeline.
// ---------------------------------------------------------------------------
__global__ __launch_bounds__(256, 1) void k_lingemm(
    const bf16* __restrict__ Ac, const bf16* __restrict__ Wl,
    const float* __restrict__ blin, float* __restrict__ out)
{
    __shared__ __align__(16) uint8_t smem[98304];
    bf16* sA = (bf16*)smem;
    bf16* sB = (bf16*)(smem + 49152);

    const int tid = threadIdx.x, lane = tid & 63, w = tid >> 6;
    const int wr = w >> 1, wc = w & 1;
    const int m0 = blockIdx.x * 64, n0 = blockIdx.y * 64;
    const int kq = tid & 15, rr = tid >> 4;
    const int swz = ((kq ^ rr) << 3);

    f32x4 acc[2][2];
#pragma unroll
    for (int fn = 0; fn < 2; ++fn) {
        int np = n0 + wc * 32 + fn * 16 + (lane & 15);
        float bv = blin[np];
        f32x4 b4 = {bv, bv, bv, bv};
        acc[0][fn] = b4; acc[1][fn] = b4;
    }

    auto stage = [&](int st, int dbuf) {
        bf16* lA = sA + dbuf * 8192;
        bf16* lB = sB + dbuf * 8192;
#pragma unroll
        for (int q = 0; q < 4; ++q) {
            gl16(Ac + (size_t)(m0 + q * 16 + rr) * KL_ + st * 128 + swz, lA + q * 2048 + w * 512);
            gl16(Wl + (size_t)(n0 + q * 16 + rr) * KL_ + st * 128 + swz, lB + q * 2048 + w * 512);
        }
    };
    auto compute = [&](int dbuf) {
        const bf16* lA = sA + dbuf * 8192;
        const bf16* lB = sB + dbuf * 8192;
        short8 af[2][4], bq[2][4];
#pragma unroll
        for (int kh = 0; kh < 4; ++kh) {
            int c = kh * 4 + (lane >> 4);
            int xr = (c ^ (lane & 15)) << 3;
#pragma unroll
            for (int fm = 0; fm < 2; ++fm) {
                int r = wr * 32 + fm * 16 + (lane & 15);
                af[fm][kh] = *(const short8*)(lA + r * 128 + xr);
            }
#pragma unroll
            for (int fn = 0; fn < 2; ++fn) {
                int r = wc * 32 + fn * 16 + (lane & 15);
                bq[fn][kh] = *(const short8*)(lB + r * 128 + xr);
            }
        }
#pragma unroll
        for (int kh = 0; kh < 4; ++kh)
#pragma unroll
            for (int fm = 0; fm < 2; ++fm)
#pragma unroll
                for (int fn = 0; fn < 2; ++fn)
                    acc[fm][fn] = __builtin_amdgcn_mfma_f32_16x16x32_bf16(
                        af[fm][kh], bq[fn][kh], acc[fm][fn], 0, 0, 0);
    };

    stage(0, 0);
    stage(1, 1);
    PIPE_BARRIER_COUNTED();

    int cur = 0;
#pragma unroll 1
    for (int st = 0; st < 49; ++st) {
        int pre = cur + 2; if (pre >= 3) pre -= 3;
        if (st + 2 < 49) stage(st + 2, pre);
        compute(cur);
        if (st + 2 < 49) { PIPE_BARRIER_COUNTED(); }
        else             { PIPE_BARRIER_DRAIN(); }
        ++cur; if (cur == 3) cur = 0;
    }

#pragma unroll
    for (int fm = 0; fm < 2; ++fm)
#pragma unroll
        for (int fn = 0; fn < 2; ++fn) {
            int col = n0 + wc * 32 + fn * 16 + (lane & 15);
            int rb  = m0 + wr * 32 + fm * 16 + ((lane >> 4) << 2);
#pragma unroll
            for (int j = 0; j < 4; ++j)
                out[(size_t)(rb + j) * N_ + col] = fmaxf(acc[fm][fn][j], 0.f);
        }
}

// ---------------------------------------------------------------------------
// Weight prep: split Wconv into Wx/Wh, n' = 4c+gate rows, k = kid*128+ic
// ---------------------------------------------------------------------------
__global__ __launch_bounds__(256) void k_wsplit(const float* __restrict__ Wc,
                                               bf16* __restrict__ WxP, bf16* __restrict__ WhP) {
    int idx = blockIdx.x * 256 + threadIdx.x;     // 512*288
    if (idx >= 512 * 288) return;
    int np = idx / 288, kq = idx % 288;
    int oc = ((np & 3) << 7) + (np >> 2);
    int kk = kq * 8;
    int half = kk >= KH_;
    int krel = kk - half * KH_;
    short8 v;
#pragma unroll
    for (int j = 0; j < 8; ++j) {
        int kr = krel + j;
        int kid = kr >> 7, ic = (kr & 127) + half * 128;
        bfbits bb; bb.b = __float2bfloat16(Wc[((size_t)oc * 256 + ic) * 9 + kid]);
        v[j] = bb.s;
    }
    bf16* dst = half ? WhP : WxP;
    *reinterpret_cast<short8*>(dst + (size_t)np * KH_ + krel) = v;
}

// Wlin reorder: k' = s*128+c
__global__ __launch_bounds__(256) void k_wlin2(const float* __restrict__ Wl, bf16* __restrict__ Wp) {
    int idx = blockIdx.x * 256 + threadIdx.x;     // 512*784
    if (idx >= 512 * 784) return;
    int np = idx / 784, kq = idx % 784;
    short8 v;
#pragma unroll
    for (int j = 0; j < 8; ++j) {
        int kp = kq * 8 + j;
        int s = kp >> 7, c = kp & 127;
        bfbits bb; bb.b = __float2bfloat16(Wl[(size_t)np * KL_ + c * S_ + s]);
        v[j] = bb.s;
    }
    *reinterpret_cast<short8*>(Wp + (size_t)np * KL_ + kq * 8) = v;
}

// x (T*B, C, 49) f32 -> xT (T*B, 49, 128) bf16
__global__ __launch_bounds__(256) void k_xpose(const float* __restrict__ x, bf16* __restrict__ xT) {
    int idx = blockIdx.x * 256 + threadIdx.x;     // 1024*784
    if (idx >= 1024 * 784) return;
    int r = idx / 784;
    int rem = idx % 784;
    int s = rem / 16, c8 = (rem & 15) * 8;
    const float* sp = x + (size_t)r * CS_ + c8 * S_ + s;
    short8 v;
#pragma unroll
    for (int j = 0; j < 8; ++j) { bfbits bb; bb.b = __float2bfloat16(sp[j * S_]); v[j] = bb.s; }
    *reinterpret_cast<short8*>(xT + (((size_t)r * S_ + s) << 7) + c8) = v;
}

// h0*mask0 -> hT bf16 (b,s,c);  c0 -> cbuf f32 (b,s,c)
__global__ __launch_bounds__(256) void k_hcprep(const float* __restrict__ hxs,
                                                const float* __restrict__ mask0,
                                                bf16* __restrict__ hT, float* __restrict__ cbuf) {
    int idx = blockIdx.x * 256 + threadIdx.x;     // 32*784
    if (idx >= 32 * 784) return;
    int b = idx / 784;
    int rem = idx % 784;
    int s = rem / 16, c8 = (rem & 15) * 8;
    float m = mask0[b];
    const float* hp = hxs + (size_t)b * ICS_ + c8 * S_ + s;
    const float* cp = hp + CS_;
    size_t o = (((size_t)b * S_ + s) << 7) + c8;
    short8 v;
#pragma unroll
    for (int j = 0; j < 8; ++j) {
        bfbits bb; bb.b = __float2bfloat16(hp[j * S_] * m); v[j] = bb.s;
        cbuf[o + j] = cp[j * S_];
    }
    *reinterpret_cast<short8*>(hT + o) = v;
}

__global__ __launch_bounds__(256) void k_zero16(uint4* __restrict__ p, int n) {
    int i = blockIdx.x * 256 + threadIdx.x;
    if (i < n) p[i] = make_uint4(0, 0, 0, 0);
}

// final state: out[b][ch][s], ch<128 from hT bf16, else cbuf f32 (both (b,s,c))
__global__ __launch_bounds__(256) void k_final(const bf16* __restrict__ hT, const float* __restrict__ cbuf,
                                               float* __restrict__ out) {
    int i = blockIdx.x * 256 + threadIdx.x;       // 32*12544
    if (i >= B_ * ICS_) return;
    int b = i / ICS_, r = i % ICS_;
    int ch = r / S_, s = r % S_;
    size_t o = (((size_t)b * S_ + s) << 7);
    out[i] = (ch < C_) ? __bfloat162float(hT[o + ch]) : cbuf[o + (ch - C_)];
}

extern "C" void kernel_launch(void* const* d_in, const int* in_sizes, int n_in,
                              void* d_out, int out_size, void* d_ws, size_t ws_size,
                              hipStream_t stream) {
    (void)in_sizes; (void)n_in; (void)out_size; (void)ws_size;
    const float* x     = (const float*)d_in[0];
    const float* hxs   = (const float*)d_in[1];
    const float* masks = (const float*)d_in[2];
    const float* Wconv = (const float*)d_in[3];
    const float* bconv = (const float*)d_in[4];
    const float* Wlin  = (const float*)d_in[5];
    const float* blin  = (const float*)d_in[6];
    float* out = (float*)d_out;

    uint8_t* p = (uint8_t*)d_ws;
    bf16* WxP   = (bf16*)p;   p += (size_t)512 * KH_ * 2;        // 1.18 MB
    bf16* WhP   = (bf16*)p;   p += (size_t)512 * KH_ * 2;        // 1.18 MB
    bf16* Wlp   = (bf16*)p;   p += (size_t)512 * KL_ * 2;        // 6.42 MB
    bf16* xT    = (bf16*)p;   p += (size_t)1024 * S_ * C_ * 2;   // 12.85 MB
    bf16* hA    = (bf16*)p;   p += (size_t)B_ * S_ * C_ * 2;     // 0.40 MB
    bf16* hB    = (bf16*)p;   p += (size_t)B_ * S_ * C_ * 2;     // 0.40 MB
    float* cbuf = (float*)p;  p += (size_t)B_ * S_ * C_ * 4;     // 0.80 MB
    float* Gx   = (float*)p;  p += (size_t)MR_ * N_ * 4;         // 3.28 MB
    bf16* chist = (bf16*)p;   p += (size_t)1024 * KL_ * 2;       // 12.85 MB
    bf16* zb    = (bf16*)p;   p += 1024;                         // zero page
    bf16* hbufs[2] = {hA, hB};

    k_wsplit<<<576, 256, 0, stream>>>(Wconv, WxP, WhP);
    k_wlin2<<<1568, 256, 0, stream>>>(Wlin, Wlp);
    k_xpose<<<3136, 256, 0, stream>>>(x, xT);
    k_hcprep<<<98, 256, 0, stream>>>(hxs, masks, hA, cbuf);
    k_zero16<<<1, 256, 0, stream>>>((uint4*)zb, 64);

    int g = 0;
    for (int t = 0; t < T_; ++t) {
        const bf16* xTt = xT + (size_t)t * B_ * S_ * C_;
        for (int rd = 0; rd < 3; ++rd) {
            const float* mc = (rd == 0) ? masks + (size_t)t * B_ : nullptr;
            const float* ma = (rd == 2 && t < T_ - 1) ? masks + (size_t)(t + 1) * B_ : nullptr;
            bf16* ct = (rd == 2) ? chist + (size_t)t * B_ * KL_ : nullptr;
            k_fgemm<<<dim3(25, 8), 256, 0, stream>>>(
                (rd == 0) ? xTt : nullptr, hbufs[g & 1], hbufs[(g + 1) & 1],
                WxP, WhP, bconv, Gx, cbuf, mc, ma, ct, zb, (rd == 0) ? 1 : 0);
            ++g;
        }
    }

    k_lingemm<<<dim3(16, 8), 256, 0, stream>>>(chist, Wlp, blin, out);
    k_final<<<1568, 256, 0, stream>>>(hbufs[0], cbuf, out + (size_t)T_ * B_ * HS_);
}